// Round 2
// baseline (462.462 us; speedup 1.0000x reference)
//
#include <hip/hip_runtime.h>

// Fully-fused undecimated starlet analysis, 4 scales, separable [1,4,6,4,1]/16,
// dilation 2^s, symmetric boundary. ONE kernel: stage 124^2 region into LDS,
// per scale: horizontal dilated 5-tap (A->B), stash central low (A->S),
// vertical 5-tap via residue-chain streaming (runs of 8 outputs, rolling
// 5-register window: each B row read ONCE instead of 5x) + coeff store.
//
// Round-2 changes vs round-1 (LDS-throughput-bound at ~24k LDS cyc/tile):
//  - v_pass: residue-chain runs-of-8 w/ rolling window: 785 -> 236 wave-reads/tile
//  - staging: float2 global + ds_write_b64 for interior tiles (scalar mirror
//    path only for the 60/256 border tiles)
//  - copy_central: vectorized (b128, b64-pair for the PMIN%4!=0 scale)

#define IMG    1024
#define NBATCH 16
#define TILE   64
#define RTOT   30                 // 2*(1+2+4+8) cumulative halo
#define SA     (TILE + 2 * RTOT)  // 124: staged side == A stride
#define BS     1024

static_assert(SA == 124, "halo arithmetic");

__device__ __forceinline__ int mirror_idx(int g, int n) {
    g = (g < 0) ? (-1 - g) : g;
    g = (g >= n) ? (2 * n - 1 - g) : g;
    return g;
}

__device__ __forceinline__ float4 tap5(float4 q0, float4 q1, float4 q2,
                                       float4 q3, float4 q4) {
    float4 o;
    o.x = 0.375f * q2.x + 0.25f * (q1.x + q3.x) + 0.0625f * (q0.x + q4.x);
    o.y = 0.375f * q2.y + 0.25f * (q1.y + q3.y) + 0.0625f * (q0.y + q4.y);
    o.z = 0.375f * q2.z + 0.25f * (q1.z + q3.z) + 0.0625f * (q0.z + q4.z);
    o.w = 0.375f * q2.w + 0.25f * (q1.w + q3.w) + 0.0625f * (q0.w + q4.w);
    return o;
}

// Horizontal 5-tap, dilation D: A (stride SA, NIN x NIN) -> B (stride NOUT).
// One output quad per work item; lanes contiguous along x -> conflict-free.
template <int D, int NIN>
__device__ __forceinline__ void h_pass(const float* __restrict__ A,
                                       float* __restrict__ B, int tid) {
    constexpr int NOUT = NIN - 4 * D;
    constexpr int GX = NOUT / 4;
    for (int t = tid; t < NIN * GX; t += BS) {
        const int y = t / GX;
        const int x = (t - y * GX) * 4;
        const float* row = &A[y * SA + x];
        float4 o;
        if constexpr (D == 1) {
            const float4 a = *(const float4*)(row);
            const float4 b = *(const float4*)(row + 4);
            o = tap5(a,
                     make_float4(a.y, a.z, a.w, b.x),
                     make_float4(a.z, a.w, b.x, b.y),
                     make_float4(a.w, b.x, b.y, b.z),
                     b);
        } else if constexpr (D == 2) {
            const float4 a = *(const float4*)(row);
            const float4 b = *(const float4*)(row + 4);
            const float4 c = *(const float4*)(row + 8);
            o = tap5(a,
                     make_float4(a.z, a.w, b.x, b.y),
                     b,
                     make_float4(b.z, b.w, c.x, c.y),
                     c);
        } else {  // D multiple of 4: every tap quad is 16B-aligned
            o = tap5(*(const float4*)(row),
                     *(const float4*)(row + D),
                     *(const float4*)(row + 2 * D),
                     *(const float4*)(row + 3 * D),
                     *(const float4*)(row + 4 * D));
        }
        *(float4*)(&B[y * NOUT + x]) = o;
    }
}

// Stash central 64^2 of low_s (vectorized). PMIN%4==2 only for scale 0.
template <int NIN>
__device__ __forceinline__ void copy_central(const float* __restrict__ A,
                                             float* __restrict__ S, int tid) {
    constexpr int PMIN = (NIN - TILE) / 2;
    for (int t = tid; t < TILE * TILE / 4; t += BS) {  // 1024 quads
        const int sy = t >> 4;
        const int sx = (t & 15) << 2;
        const float* p = &A[(PMIN + sy) * SA + PMIN + sx];
        float4 v;
        if constexpr ((PMIN & 3) != 0) {  // 8B-aligned only: two b64 reads
            const float2 a = *(const float2*)(p);
            const float2 b = *(const float2*)(p + 2);
            v = make_float4(a.x, a.y, b.x, b.y);
        } else {
            v = *(const float4*)(p);
        }
        *(float4*)(&S[sy * TILE + sx]) = v;
    }
}

// Vertical 5-tap, dilation D: residue-chain streaming. Each thread owns one
// x-quad and a run of 8 chain outputs (y = y0 + j*D, j=0..7); it streams the
// 12 covering B rows once each through a rolling 5-wide float4 window.
// Emits: new low -> A (in-place region origin), central coeff -> global.
template <int D, int NIN, bool LAST>
__device__ __forceinline__ void v_pass(float* __restrict__ A,
                                       const float* __restrict__ B,
                                       const float* __restrict__ S,
                                       float* __restrict__ gout, size_t img_off,
                                       int ty0, int tx0, float inv, int tid) {
    constexpr int NOUT = NIN - 4 * D;
    constexpr int NQ = NOUT / 4;        // x-quads
    constexpr int GY = NOUT / 8;        // row-groups (runs of 8 along chain)
    constexpr int CMIN = (NOUT - TILE) / 2;
    static_assert(NOUT % (8 * D) == 0, "chain segmentation");
    for (int t = tid; t < NQ * GY; t += BS) {
        const int xq = t % NQ;
        const int g  = t / NQ;
        const int c  = g % D;           // residue class (folds to & for pow2 D)
        const int m  = g / D;           // segment within chain
        const int y0 = c + 8 * D * m;
        const int x4 = 4 * xq;
        const bool xin = (x4 >= CMIN) && (x4 < CMIN + TILE);
        const int sx = x4 - CMIN;
        const float* bp = &B[y0 * NOUT + x4];
        float4 w0, w1, w2, w3;
        #pragma unroll
        for (int k = 0; k < 12; ++k) {
            const float4 r = *(const float4*)(bp + k * D * NOUT);
            if (k >= 4) {
                const float4 nl = tap5(w0, w1, w2, w3, r);
                const int y = y0 + (k - 4) * D;
                if constexpr (!LAST) {
                    *(float4*)(&A[y * SA + x4]) = nl;
                }
                if (xin && y >= CMIN && y < CMIN + TILE) {
                    const int sy = y - CMIN;
                    const float4 lo = *(const float4*)(&S[sy * TILE + sx]);
                    float4 cf;
                    cf.x = (lo.x - nl.x) * inv;
                    cf.y = (lo.y - nl.y) * inv;
                    cf.z = (lo.z - nl.z) * inv;
                    cf.w = (lo.w - nl.w) * inv;
                    *(float4*)(&gout[img_off + (size_t)(ty0 + sy) * IMG +
                                     (tx0 + sx)]) = cf;
                }
            }
            w0 = w1; w1 = w2; w2 = w3; w3 = r;
        }
    }
}

__global__ __launch_bounds__(BS)
void starlet_fused(const float* __restrict__ img, const float* __restrict__ norms,
                   float* __restrict__ out)
{
    __shared__ float A[SA * SA];        // 61.5 KB: staged image / running low
    __shared__ float B[SA * (SA - 4)];  // 59.5 KB: horizontal-pass tmp
    __shared__ float S[TILE * TILE];    // 16 KB: central low_s for the subtract
    // total 137.4 KB LDS -> 1 block/CU, 16 waves resident

    const int tid = threadIdx.x;
    const int tx0 = blockIdx.x * TILE;
    const int ty0 = blockIdx.y * TILE;
    const size_t img_off = (size_t)blockIdx.z * (size_t)(IMG * IMG);
    const size_t plane = (size_t)NBATCH * IMG * IMG;

    const float i0 = 1.0f / norms[0];
    const float i1 = 1.0f / norms[1];
    const float i2 = 1.0f / norms[2];
    const float i3 = 1.0f / norms[3];

    // ---- stage 124^2 region ----
    const bool interior = (blockIdx.x >= 1) && (blockIdx.x <= 14) &&
                          (blockIdx.y >= 1) && (blockIdx.y <= 14);
    if (interior) {
        // no mirroring needed: float2 global loads (8B-aligned) + b64 LDS writes
        const float* src = img + img_off + (size_t)(ty0 - RTOT) * IMG + (tx0 - RTOT);
        for (int t = tid; t < SA * SA / 2; t += BS) {  // 7688 float2s
            const int ry  = t / (SA / 2);
            const int rx2 = (t - ry * (SA / 2)) * 2;
            const float2 v = *(const float2*)(src + (size_t)ry * IMG + rx2);
            *(float2*)(&A[ry * SA + rx2]) = v;
        }
    } else {
        for (int i = tid; i < SA * SA; i += BS) {
            const int ry = i / SA;
            const int rx = i - ry * SA;
            const int gy = mirror_idx(ty0 - RTOT + ry, IMG);
            const int gx = mirror_idx(tx0 - RTOT + rx, IMG);
            A[i] = img[img_off + (size_t)gy * IMG + gx];
        }
    }
    __syncthreads();

    // ---- scale 0: D=1, 124 -> 120 ----
    h_pass<1, 124>(A, B, tid);
    copy_central<124>(A, S, tid);
    __syncthreads();
    v_pass<1, 124, false>(A, B, S, out, img_off, ty0, tx0, i0, tid);
    __syncthreads();

    // ---- scale 1: D=2, 120 -> 112 ----
    h_pass<2, 120>(A, B, tid);
    copy_central<120>(A, S, tid);
    __syncthreads();
    v_pass<2, 120, false>(A, B, S, out + plane, img_off, ty0, tx0, i1, tid);
    __syncthreads();

    // ---- scale 2: D=4, 112 -> 96 ----
    h_pass<4, 112>(A, B, tid);
    copy_central<112>(A, S, tid);
    __syncthreads();
    v_pass<4, 112, false>(A, B, S, out + 2 * plane, img_off, ty0, tx0, i2, tid);
    __syncthreads();

    // ---- scale 3: D=8, 96 -> 64 (low4 discarded) ----
    h_pass<8, 96>(A, B, tid);
    copy_central<96>(A, S, tid);
    __syncthreads();
    v_pass<8, 96, true>(A, B, S, out + 3 * plane, img_off, ty0, tx0, i3, tid);
}

extern "C" void kernel_launch(void* const* d_in, const int* in_sizes, int n_in,
                              void* d_out, int out_size, void* d_ws, size_t ws_size,
                              hipStream_t stream) {
    const float* image = (const float*)d_in[0];
    const float* norms = (const float*)d_in[1];
    float* out = (float*)d_out;

    dim3 grid(IMG / TILE, IMG / TILE, NBATCH);
    starlet_fused<<<grid, dim3(BS), 0, stream>>>(image, norms, out);
}